// Round 9
// baseline (208.240 us; speedup 1.0000x reference)
//
#include <hip/hip_runtime.h>
#include <hip/hip_bf16.h>

// GCNConv: out = segment_sum(edge_vals * (x@W)[edge_col], edge_row)
// Fused: {h = x@W bf16 MFMA, 32-row waves, 782 blocks} + {rank pass,
// 256 grid-stride blocks, 4 atomics in flight/thread} -> co-resident overlap.
// Then: scan -> atomic-free scatter (4B packed: val_q15:15 | col:17) ->
// rowsum (1 row/wave, staged 64-edge batches, shfl broadcast, x4 unroll).
// Packing assumes n_nodes < 2^17 and edge_vals in [0,1).

#define IN_F  256
#define OUT_F 128

typedef __attribute__((ext_vector_type(8))) short sh8;
typedef __attribute__((ext_vector_type(4))) float f32x4;

__device__ __forceinline__ unsigned short f2bf(float f) {
    unsigned u = __float_as_uint(f);
    unsigned r = u + 0x7fff + ((u >> 16) & 1);   // round-to-nearest-even
    return (unsigned short)(r >> 16);
}
__device__ __forceinline__ float bf2f(unsigned short s) {
    return __uint_as_float(((unsigned)s) << 16);
}

// ---------------- Wt[n][k] = bf16(W[k][n]) ----------------
__global__ __launch_bounds__(256) void wt_prep_kernel(
    const float* __restrict__ w, unsigned short* __restrict__ wt) {
    int i = blockIdx.x * 256 + threadIdx.x;     // 32768 elements
    int k = i >> 7, n = i & 127;
    wt[n * IN_F + k] = f2bf(w[i]);
}

// ---------------- Fused: rank (g < rank_blocks) + gemm ----------------
__global__ __launch_bounds__(256) void fused_gemm_rank_kernel(
    const float* __restrict__ x, const unsigned short* __restrict__ wt,
    unsigned short* __restrict__ h, int n_nodes,
    const int* __restrict__ erow, int* __restrict__ counts,
    unsigned char* __restrict__ rank, int n_edges, int rank_blocks) {
    int g = blockIdx.x;
    int tid = threadIdx.x;

    if (g < rank_blocks) {
        // ---------- RANK: grid-stride, 4 edges (1 int4) per iteration ------
        int stride = rank_blocks * 256;
        int n4 = n_edges >> 2;
        for (int i = g * 256 + tid; i < n4; i += stride) {
            int4 r = ((const int4*)erow)[i];
            uchar4 k;
            k.x = (unsigned char)atomicAdd(&counts[r.x], 1);
            k.y = (unsigned char)atomicAdd(&counts[r.y], 1);
            k.z = (unsigned char)atomicAdd(&counts[r.z], 1);
            k.w = (unsigned char)atomicAdd(&counts[r.w], 1);
            ((uchar4*)rank)[i] = k;
        }
        for (int i = (n4 << 2) + g * 256 + tid; i < n_edges; i += stride)
            rank[i] = (unsigned char)atomicAdd(&counts[erow[i]], 1);
    } else {
        // ---------- GEMM: 32-row waves, 128 rows per block (R5 shape) ------
        int gb = g - rank_blocks;
        int wv = tid >> 6, l = tid & 63;
        int l16 = l & 15, lk = (l >> 4) * 8;
        long row0 = (long)gb * 128 + wv * 32;

        long rmax = n_nodes - 1;
        long ra0 = row0 + l16;      if (ra0 > rmax) ra0 = rmax;
        long ra1 = row0 + 16 + l16; if (ra1 > rmax) ra1 = rmax;
        const float* xp0 = x + ra0 * IN_F + lk;
        const float* xp1 = x + ra1 * IN_F + lk;
        const unsigned short* wp = wt + l16 * IN_F + lk;

        f32x4 acc[2][8];
        #pragma unroll
        for (int rt = 0; rt < 2; rt++)
            #pragma unroll
            for (int nt = 0; nt < 8; nt++)
                acc[rt][nt] = (f32x4){0.f, 0.f, 0.f, 0.f};

        #pragma unroll
        for (int ks = 0; ks < 8; ks++) {
            int k0 = ks * 32;
            float4 t0 = *(const float4*)(xp0 + k0);
            float4 t1 = *(const float4*)(xp0 + k0 + 4);
            float4 t2 = *(const float4*)(xp1 + k0);
            float4 t3 = *(const float4*)(xp1 + k0 + 4);
            sh8 a0, a1;
            a0[0] = (short)f2bf(t0.x); a0[1] = (short)f2bf(t0.y);
            a0[2] = (short)f2bf(t0.z); a0[3] = (short)f2bf(t0.w);
            a0[4] = (short)f2bf(t1.x); a0[5] = (short)f2bf(t1.y);
            a0[6] = (short)f2bf(t1.z); a0[7] = (short)f2bf(t1.w);
            a1[0] = (short)f2bf(t2.x); a1[1] = (short)f2bf(t2.y);
            a1[2] = (short)f2bf(t2.z); a1[3] = (short)f2bf(t2.w);
            a1[4] = (short)f2bf(t3.x); a1[5] = (short)f2bf(t3.y);
            a1[6] = (short)f2bf(t3.z); a1[7] = (short)f2bf(t3.w);
            #pragma unroll
            for (int nt = 0; nt < 8; nt++) {
                sh8 b = *(const sh8*)(wp + nt * 16 * IN_F + k0);
                acc[0][nt] = __builtin_amdgcn_mfma_f32_16x16x32_bf16(
                    a0, b, acc[0][nt], 0, 0, 0);
                acc[1][nt] = __builtin_amdgcn_mfma_f32_16x16x32_bf16(
                    a1, b, acc[1][nt], 0, 0, 0);
            }
        }

        int rbase = (l >> 4) * 4;
        #pragma unroll
        for (int rt = 0; rt < 2; rt++) {
            #pragma unroll
            for (int j = 0; j < 4; j++) {
                long r = row0 + rt * 16 + rbase + j;
                if (r < n_nodes) {
                    unsigned short* hp = h + r * OUT_F + l16;
                    #pragma unroll
                    for (int nt = 0; nt < 8; nt++)
                        hp[nt * 16] = f2bf(acc[rt][nt][j]);
                }
            }
        }
    }
}

__global__ __launch_bounds__(256) void scan1_kernel(
    const int* __restrict__ counts, int* __restrict__ excl,
    int* __restrict__ partials, int n) {
    __shared__ int s[256];
    int tid = threadIdx.x;
    int i = blockIdx.x * 256 + tid;
    int v = (i < n) ? counts[i] : 0;
    s[tid] = v;
    __syncthreads();
    for (int off = 1; off < 256; off <<= 1) {
        int t = (tid >= off) ? s[tid - off] : 0;
        __syncthreads();
        s[tid] += t;
        __syncthreads();
    }
    if (i < n) excl[i] = s[tid] - v;
    if (tid == 255) partials[blockIdx.x] = s[255];
}

__global__ __launch_bounds__(512) void scan2_kernel(int* partials, int nb) {
    __shared__ int s[512];
    int tid = threadIdx.x;
    int v = (tid < nb) ? partials[tid] : 0;
    s[tid] = v;
    __syncthreads();
    for (int off = 1; off < 512; off <<= 1) {
        int t = (tid >= off) ? s[tid - off] : 0;
        __syncthreads();
        s[tid] += t;
        __syncthreads();
    }
    if (tid < nb) partials[tid] = s[tid] - v;
}

__global__ __launch_bounds__(256) void scan3_kernel(
    int* __restrict__ excl, const int* __restrict__ partials, int n) {
    int i = blockIdx.x * 256 + threadIdx.x;
    if (i < n) excl[i] += partials[blockIdx.x];
}

// ---------------- atomic-free scatter, 4B packed edges ----------------
__device__ __forceinline__ unsigned pack_edge(float v, int c) {
    unsigned q = (unsigned)__builtin_fmaf(v, 32767.f, 0.5f);
    return (q << 17) | (unsigned)c;
}

__global__ __launch_bounds__(256) void scatter_kernel(
    const int* __restrict__ erow, const int* __restrict__ ecol,
    const float* __restrict__ eval, const unsigned char* __restrict__ rank,
    const int* __restrict__ offs, unsigned* __restrict__ epack,
    int n_edges) {
    int stride = gridDim.x * 256;
    int n4 = n_edges >> 2;
    for (int i = blockIdx.x * 256 + threadIdx.x; i < n4; i += stride) {
        int4   r = ((const int4*)erow)[i];
        int4   c = ((const int4*)ecol)[i];
        float4 v = ((const float4*)eval)[i];
        uchar4 k = ((const uchar4*)rank)[i];
        epack[offs[r.x] + k.x] = pack_edge(v.x, c.x);
        epack[offs[r.y] + k.y] = pack_edge(v.y, c.y);
        epack[offs[r.z] + k.z] = pack_edge(v.z, c.z);
        epack[offs[r.w] + k.w] = pack_edge(v.w, c.w);
    }
    for (int i = (n4 << 2) + blockIdx.x * 256 + threadIdx.x; i < n_edges;
         i += stride) {
        epack[offs[erow[i]] + rank[i]] = pack_edge(eval[i], ecol[i]);
    }
}

// ---------------- rowsum: 1 row/wave, staged 64-edge batches ----------------
__global__ __launch_bounds__(256) void rowsum_kernel(
    const unsigned short* __restrict__ h, const int* __restrict__ offs,
    const unsigned* __restrict__ epack,
    float* __restrict__ out, int n_nodes, int n_edges) {
    int wid = (blockIdx.x * 256 + threadIdx.x) >> 6;
    int lane = threadIdx.x & 63;
    if (wid >= n_nodes) return;

    int s = offs[wid];
    int e = (wid + 1 < n_nodes) ? offs[wid + 1] : n_edges;
    int cnt = e - s;

    const float dq = 1.0f / 32767.f;
    float a0 = 0.f, a1 = 0.f;
    for (int base = 0; base < cnt; base += 64) {
        int m = min(64, cnt - base);
        unsigned pk = 0;
        if (base + lane < cnt) pk = epack[s + base + lane];

        int j = 0;
        for (; j + 4 <= m; j += 4) {
            unsigned p0 = __shfl(pk, j);
            unsigned p1 = __shfl(pk, j + 1);
            unsigned p2 = __shfl(pk, j + 2);
            unsigned p3 = __shfl(pk, j + 3);
            unsigned hv0 = *((const unsigned*)(h + (long)(p0 & 0x1ffffu) * OUT_F) + lane);
            unsigned hv1 = *((const unsigned*)(h + (long)(p1 & 0x1ffffu) * OUT_F) + lane);
            unsigned hv2 = *((const unsigned*)(h + (long)(p2 & 0x1ffffu) * OUT_F) + lane);
            unsigned hv3 = *((const unsigned*)(h + (long)(p3 & 0x1ffffu) * OUT_F) + lane);
            float v0 = (float)(p0 >> 17) * dq;
            float v1 = (float)(p1 >> 17) * dq;
            float v2 = (float)(p2 >> 17) * dq;
            float v3 = (float)(p3 >> 17) * dq;
            a0 += v0 * bf2f((unsigned short)(hv0 & 0xffff));
            a1 += v0 * bf2f((unsigned short)(hv0 >> 16));
            a0 += v1 * bf2f((unsigned short)(hv1 & 0xffff));
            a1 += v1 * bf2f((unsigned short)(hv1 >> 16));
            a0 += v2 * bf2f((unsigned short)(hv2 & 0xffff));
            a1 += v2 * bf2f((unsigned short)(hv2 >> 16));
            a0 += v3 * bf2f((unsigned short)(hv3 & 0xffff));
            a1 += v3 * bf2f((unsigned short)(hv3 >> 16));
        }
        for (; j < m; j++) {
            unsigned p0 = __shfl(pk, j);
            unsigned hv0 = *((const unsigned*)(h + (long)(p0 & 0x1ffffu) * OUT_F) + lane);
            float v0 = (float)(p0 >> 17) * dq;
            a0 += v0 * bf2f((unsigned short)(hv0 & 0xffff));
            a1 += v0 * bf2f((unsigned short)(hv0 >> 16));
        }
    }
    float2 o; o.x = a0; o.y = a1;
    *(float2*)(out + (long)wid * OUT_F + lane * 2) = o;
}

extern "C" void kernel_launch(void* const* d_in, const int* in_sizes, int n_in,
                              void* d_out, int out_size, void* d_ws, size_t ws_size,
                              hipStream_t stream) {
    const float* x    = (const float*)d_in[0];
    const float* w    = (const float*)d_in[1];
    const int*   erow = (const int*)d_in[2];
    const int*   ecol = (const int*)d_in[3];
    const float* eval = (const float*)d_in[4];
    float* out = (float*)d_out;

    int n_nodes = in_sizes[0] / IN_F;
    int n_edges = in_sizes[2];
    int nb = (n_nodes + 255) / 256;
    int n4 = n_edges >> 2;
    int eblk = (n4 + 255) / 256;

    // workspace layout (256B aligned)
    char* p = (char*)d_ws;
    auto alloc = [&](size_t bytes) {
        char* q = p;
        p += (bytes + 255) & ~(size_t)255;
        return q;
    };
    unsigned short* h  = (unsigned short*)alloc((size_t)n_nodes * OUT_F * 2);
    int*   counts   = (int*)alloc((size_t)n_nodes * 4);
    int*   offs     = (int*)alloc((size_t)n_nodes * 4);
    int*   partials = (int*)alloc((size_t)nb * 4);
    unsigned* epack = (unsigned*)alloc((size_t)n_edges * 4);
    unsigned char* rank = (unsigned char*)alloc((size_t)n_edges);
    unsigned short* wt  = (unsigned short*)alloc((size_t)IN_F * OUT_F * 2);

    hipMemsetAsync(counts, 0, (size_t)n_nodes * 4, stream);

    wt_prep_kernel<<<dim3((IN_F * OUT_F) / 256), 256, 0, stream>>>(w, wt);

    int rank_blocks = 256;                         // 1024 waves = 4/CU
    int gemm_blocks = (n_nodes + 127) / 128;       // 782
    fused_gemm_rank_kernel<<<dim3(rank_blocks + gemm_blocks), 256, 0, stream>>>(
        x, wt, h, n_nodes, erow, counts, rank, n_edges, rank_blocks);

    scan1_kernel<<<dim3(nb), 256, 0, stream>>>(counts, offs, partials, n_nodes);
    scan2_kernel<<<dim3(1), 512, 0, stream>>>(partials, nb);
    scan3_kernel<<<dim3(nb), 256, 0, stream>>>(offs, partials, n_nodes);
    scatter_kernel<<<dim3(eblk), 256, 0, stream>>>(erow, ecol, eval, rank,
                                                   offs, epack, n_edges);

    rowsum_kernel<<<dim3(((long)n_nodes * 64 + 255) / 256), 256, 0, stream>>>(
        h, offs, epack, out, n_nodes, n_edges);
}

// Round 10
// 166.188 us; speedup vs baseline: 1.2530x; 1.2530x over previous
//
#include <hip/hip_runtime.h>
#include <hip/hip_bf16.h>

// GCNConv: out = segment_sum(edge_vals * (x@W)[edge_col], edge_row)
// Phase 1: Wt = bf16(W^T); h = x@W via bf16 MFMA (32-row waves).
// Phase 2: ATOMIC-FREE bucket counting sort (bucket = 64 rows):
//   hist  : per-4096-edge-block LDS histogram -> T[block][bucket]
//   colscan: column exclusive scan of T (wave/bucket) -> per-(block,bucket) off
//   basescan: exclusive scan of bucket totals -> bucketBase
//   scatter: LDS-atomic within block, exact global position, 8B epack
//            (val fp32 : 32 | row-in-bucket : 6 | col : 17)
//   bucket_rowsum: block/bucket; LDS counting sort; 4 waves x 16 rows gather.
// No global returning atomics anywhere (the 23.5 G/s wall from R5-R8).

#define IN_F  256
#define OUT_F 128
#define BSH   6        // 64 rows per bucket
#define CH    4096     // edges per chunk block
#define CAP   1536     // LDS sorted-bucket capacity (avg 1024, +16 sigma)

typedef __attribute__((ext_vector_type(8))) short sh8;
typedef __attribute__((ext_vector_type(4))) float f32x4;

__device__ __forceinline__ unsigned short f2bf(float f) {
    unsigned u = __float_as_uint(f);
    unsigned r = u + 0x7fff + ((u >> 16) & 1);   // round-to-nearest-even
    return (unsigned short)(r >> 16);
}
__device__ __forceinline__ float bf2f(unsigned short s) {
    return __uint_as_float(((unsigned)s) << 16);
}

// ---------------- Wt[n][k] = bf16(W[k][n]) ----------------
__global__ __launch_bounds__(256) void wt_prep_kernel(
    const float* __restrict__ w, unsigned short* __restrict__ wt) {
    int i = blockIdx.x * 256 + threadIdx.x;     // 32768 elements
    int k = i >> 7, n = i & 127;
    wt[n * IN_F + k] = f2bf(w[i]);
}

// ---------------- h = x@W via MFMA (R5 shape, standalone) ----------------
__global__ __launch_bounds__(256) void gemm_mfma_kernel(
    const float* __restrict__ x, const unsigned short* __restrict__ wt,
    unsigned short* __restrict__ h, int n_nodes) {
    int tid = threadIdx.x;
    int wv = tid >> 6, l = tid & 63;
    int l16 = l & 15, lk = (l >> 4) * 8;
    long row0 = (long)blockIdx.x * 128 + wv * 32;

    long rmax = n_nodes - 1;
    long ra0 = row0 + l16;      if (ra0 > rmax) ra0 = rmax;
    long ra1 = row0 + 16 + l16; if (ra1 > rmax) ra1 = rmax;
    const float* xp0 = x + ra0 * IN_F + lk;
    const float* xp1 = x + ra1 * IN_F + lk;
    const unsigned short* wp = wt + l16 * IN_F + lk;

    f32x4 acc[2][8];
    #pragma unroll
    for (int rt = 0; rt < 2; rt++)
        #pragma unroll
        for (int nt = 0; nt < 8; nt++)
            acc[rt][nt] = (f32x4){0.f, 0.f, 0.f, 0.f};

    #pragma unroll
    for (int ks = 0; ks < 8; ks++) {
        int k0 = ks * 32;
        float4 t0 = *(const float4*)(xp0 + k0);
        float4 t1 = *(const float4*)(xp0 + k0 + 4);
        float4 t2 = *(const float4*)(xp1 + k0);
        float4 t3 = *(const float4*)(xp1 + k0 + 4);
        sh8 a0, a1;
        a0[0] = (short)f2bf(t0.x); a0[1] = (short)f2bf(t0.y);
        a0[2] = (short)f2bf(t0.z); a0[3] = (short)f2bf(t0.w);
        a0[4] = (short)f2bf(t1.x); a0[5] = (short)f2bf(t1.y);
        a0[6] = (short)f2bf(t1.z); a0[7] = (short)f2bf(t1.w);
        a1[0] = (short)f2bf(t2.x); a1[1] = (short)f2bf(t2.y);
        a1[2] = (short)f2bf(t2.z); a1[3] = (short)f2bf(t2.w);
        a1[4] = (short)f2bf(t3.x); a1[5] = (short)f2bf(t3.y);
        a1[6] = (short)f2bf(t3.z); a1[7] = (short)f2bf(t3.w);
        #pragma unroll
        for (int nt = 0; nt < 8; nt++) {
            sh8 b = *(const sh8*)(wp + nt * 16 * IN_F + k0);
            acc[0][nt] = __builtin_amdgcn_mfma_f32_16x16x32_bf16(
                a0, b, acc[0][nt], 0, 0, 0);
            acc[1][nt] = __builtin_amdgcn_mfma_f32_16x16x32_bf16(
                a1, b, acc[1][nt], 0, 0, 0);
        }
    }

    int rbase = (l >> 4) * 4;
    #pragma unroll
    for (int rt = 0; rt < 2; rt++) {
        #pragma unroll
        for (int j = 0; j < 4; j++) {
            long r = row0 + rt * 16 + rbase + j;
            if (r < n_nodes) {
                unsigned short* hp = h + r * OUT_F + l16;
                #pragma unroll
                for (int nt = 0; nt < 8; nt++)
                    hp[nt * 16] = f2bf(acc[rt][nt][j]);
            }
        }
    }
}

// ---------------- hist: T[b][k] = #edges of block b in bucket k -----------
__global__ __launch_bounds__(256) void hist_kernel(
    const int* __restrict__ erow, int* __restrict__ T,
    int n_edges, int nbuck) {
    __shared__ int lh[2048];
    int tid = threadIdx.x, b = blockIdx.x;
    for (int k = tid; k < nbuck; k += 256) lh[k] = 0;
    __syncthreads();
    int s = b * CH, e = min(s + CH, n_edges);
    for (int i = s + tid; i < e; i += 256)
        atomicAdd(&lh[erow[i] >> BSH], 1);
    __syncthreads();
    int* Tr = T + (long)b * nbuck;
    for (int k = tid; k < nbuck; k += 256) Tr[k] = lh[k];
}

// ---------------- colscan: T[b][k] -> prefix over b; colTotal[k] ----------
__global__ __launch_bounds__(256) void colscan_kernel(
    int* __restrict__ T, int* __restrict__ colTotal, int nblk, int nbuck) {
    int k = blockIdx.x * 4 + (threadIdx.x >> 6);
    int lane = threadIdx.x & 63;
    if (k >= nbuck) return;
    int carry = 0;
    for (int c = 0; c < nblk; c += 64) {
        int b = c + lane;
        int v = (b < nblk) ? T[(long)b * nbuck + k] : 0;
        int incl = v;
        #pragma unroll
        for (int off = 1; off < 64; off <<= 1) {
            int t = __shfl_up(incl, off);
            if (lane >= off) incl += t;
        }
        if (b < nblk) T[(long)b * nbuck + k] = carry + incl - v;
        carry += __shfl(incl, 63);
    }
    if (lane == 0) colTotal[k] = carry;
}

// ---------------- basescan: bucketBase = exclusive scan(colTotal) ---------
__global__ __launch_bounds__(256) void basescan_kernel(
    const int* __restrict__ colTotal, int* __restrict__ base, int nbuck) {
    __shared__ int s[256];
    int tid = threadIdx.x;
    int loc[8];
    int sum = 0;
    #pragma unroll
    for (int j = 0; j < 8; j++) {
        int i = tid * 8 + j;
        loc[j] = (i < nbuck) ? colTotal[i] : 0;
        sum += loc[j];
    }
    s[tid] = sum;
    __syncthreads();
    for (int off = 1; off < 256; off <<= 1) {
        int t = (tid >= off) ? s[tid - off] : 0;
        __syncthreads();
        s[tid] += t;
        __syncthreads();
    }
    int pre = s[tid] - sum;
    #pragma unroll
    for (int j = 0; j < 8; j++) {
        int i = tid * 8 + j;
        if (i < nbuck) base[i] = pre;
        pre += loc[j];
    }
    if (tid == 255) base[nbuck] = pre;    // == n_edges
}

// ---------------- scatter: exact positions via LDS atomics ----------------
__global__ __launch_bounds__(256) void scatter_kernel(
    const int* __restrict__ erow, const int* __restrict__ ecol,
    const float* __restrict__ eval, const int* __restrict__ T,
    const int* __restrict__ base, unsigned long long* __restrict__ epack,
    int n_edges, int nbuck) {
    __shared__ int lpos[2048];
    int tid = threadIdx.x, b = blockIdx.x;
    const int* Tr = T + (long)b * nbuck;
    for (int k = tid; k < nbuck; k += 256) lpos[k] = base[k] + Tr[k];
    __syncthreads();
    int s = b * CH, e = min(s + CH, n_edges);
    for (int i = s + tid; i < e; i += 256) {
        int r = erow[i];
        int c = ecol[i];
        float v = eval[i];
        int p = atomicAdd(&lpos[r >> BSH], 1);
        epack[p] = ((unsigned long long)__float_as_uint(v) << 32)
                 | ((unsigned)(r & 63) << 17) | (unsigned)c;
    }
}

// ---------------- bucket_rowsum: block/bucket, LDS sort, gather -----------
__global__ __launch_bounds__(256) void bucket_rowsum_kernel(
    const unsigned short* __restrict__ h, const int* __restrict__ base,
    const unsigned long long* __restrict__ epack,
    float* __restrict__ out, int n_nodes, int nbuck) {
    __shared__ unsigned long long sorted[CAP];
    __shared__ int lh[64], lo[64], lc[64];
    int tid = threadIdx.x, k = blockIdx.x;
    int s = base[k], e = base[k + 1];
    int size = e - s;
    int wv = tid >> 6, lane = tid & 63;

    if (tid < 64) { lh[tid] = 0; lc[tid] = 0; }
    __syncthreads();
    for (int i = tid; i < size; i += 256) {
        unsigned lo32 = (unsigned)(epack[s + i] & 0xffffffffu);
        atomicAdd(&lh[(lo32 >> 17) & 63], 1);
    }
    __syncthreads();
    if (tid < 64) {
        int v = lh[tid];
        int incl = v;
        #pragma unroll
        for (int off = 1; off < 64; off <<= 1) {
            int t = __shfl_up(incl, off);
            if (lane >= off) incl += t;
        }
        lo[tid] = incl - v;
    }
    __syncthreads();
    bool fits = (size <= CAP);
    if (fits) {
        for (int i = tid; i < size; i += 256) {
            unsigned long long ed = epack[s + i];
            int r = (int)((ed >> 17) & 63);
            int p = atomicAdd(&lc[r], 1) + lo[r];
            sorted[p] = ed;
        }
    }
    __syncthreads();

    for (int rr = 0; rr < 16; rr++) {
        int r = wv * 16 + rr;
        long row = (long)k * 64 + r;
        if (row >= n_nodes) break;
        int rs = lo[r], cnt = lh[r];
        float a0 = 0.f, a1 = 0.f;
        if (fits) {
            int j = 0;
            for (; j + 4 <= cnt; j += 4) {
                unsigned long long e0 = sorted[rs + j];
                unsigned long long e1 = sorted[rs + j + 1];
                unsigned long long e2 = sorted[rs + j + 2];
                unsigned long long e3 = sorted[rs + j + 3];
                unsigned hv0 = *((const unsigned*)(h + (long)(e0 & 0x1ffffu) * OUT_F) + lane);
                unsigned hv1 = *((const unsigned*)(h + (long)(e1 & 0x1ffffu) * OUT_F) + lane);
                unsigned hv2 = *((const unsigned*)(h + (long)(e2 & 0x1ffffu) * OUT_F) + lane);
                unsigned hv3 = *((const unsigned*)(h + (long)(e3 & 0x1ffffu) * OUT_F) + lane);
                float v0 = __uint_as_float((unsigned)(e0 >> 32));
                float v1 = __uint_as_float((unsigned)(e1 >> 32));
                float v2 = __uint_as_float((unsigned)(e2 >> 32));
                float v3 = __uint_as_float((unsigned)(e3 >> 32));
                a0 += v0 * bf2f((unsigned short)(hv0 & 0xffff));
                a1 += v0 * bf2f((unsigned short)(hv0 >> 16));
                a0 += v1 * bf2f((unsigned short)(hv1 & 0xffff));
                a1 += v1 * bf2f((unsigned short)(hv1 >> 16));
                a0 += v2 * bf2f((unsigned short)(hv2 & 0xffff));
                a1 += v2 * bf2f((unsigned short)(hv2 >> 16));
                a0 += v3 * bf2f((unsigned short)(hv3 & 0xffff));
                a1 += v3 * bf2f((unsigned short)(hv3 >> 16));
            }
            for (; j < cnt; j++) {
                unsigned long long e0 = sorted[rs + j];
                unsigned hv0 = *((const unsigned*)(h + (long)(e0 & 0x1ffffu) * OUT_F) + lane);
                float v0 = __uint_as_float((unsigned)(e0 >> 32));
                a0 += v0 * bf2f((unsigned short)(hv0 & 0xffff));
                a1 += v0 * bf2f((unsigned short)(hv0 >> 16));
            }
        } else {
            // never expected for this data; correct fallback
            for (int i = 0; i < size; i++) {
                unsigned long long ed = epack[s + i];
                if ((int)((ed >> 17) & 63) == r) {
                    unsigned hv0 = *((const unsigned*)(h + (long)(ed & 0x1ffffu) * OUT_F) + lane);
                    float v0 = __uint_as_float((unsigned)(ed >> 32));
                    a0 += v0 * bf2f((unsigned short)(hv0 & 0xffff));
                    a1 += v0 * bf2f((unsigned short)(hv0 >> 16));
                }
            }
        }
        float2 o; o.x = a0; o.y = a1;
        *(float2*)(out + row * OUT_F + lane * 2) = o;
    }
}

extern "C" void kernel_launch(void* const* d_in, const int* in_sizes, int n_in,
                              void* d_out, int out_size, void* d_ws, size_t ws_size,
                              hipStream_t stream) {
    const float* x    = (const float*)d_in[0];
    const float* w    = (const float*)d_in[1];
    const int*   erow = (const int*)d_in[2];
    const int*   ecol = (const int*)d_in[3];
    const float* eval = (const float*)d_in[4];
    float* out = (float*)d_out;

    int n_nodes = in_sizes[0] / IN_F;
    int n_edges = in_sizes[2];
    int nbuck = (n_nodes + 63) >> BSH;            // 1563
    int nblk  = (n_edges + CH - 1) / CH;          // 391

    // workspace layout (256B aligned)
    char* p = (char*)d_ws;
    auto alloc = [&](size_t bytes) {
        char* q = p;
        p += (bytes + 255) & ~(size_t)255;
        return q;
    };
    unsigned short* h  = (unsigned short*)alloc((size_t)n_nodes * OUT_F * 2);
    int* T        = (int*)alloc((size_t)nblk * nbuck * 4);
    int* colTotal = (int*)alloc((size_t)nbuck * 4);
    int* base     = (int*)alloc((size_t)(nbuck + 1) * 4);
    unsigned long long* epack = (unsigned long long*)alloc((size_t)n_edges * 8);
    unsigned short* wt = (unsigned short*)alloc((size_t)IN_F * OUT_F * 2);

    wt_prep_kernel<<<dim3((IN_F * OUT_F) / 256), 256, 0, stream>>>(w, wt);
    gemm_mfma_kernel<<<dim3((n_nodes + 127) / 128), 256, 0, stream>>>(
        x, wt, h, n_nodes);

    hist_kernel<<<dim3(nblk), 256, 0, stream>>>(erow, T, n_edges, nbuck);
    colscan_kernel<<<dim3((nbuck + 3) / 4), 256, 0, stream>>>(
        T, colTotal, nblk, nbuck);
    basescan_kernel<<<dim3(1), 256, 0, stream>>>(colTotal, base, nbuck);
    scatter_kernel<<<dim3(nblk), 256, 0, stream>>>(
        erow, ecol, eval, T, base, epack, n_edges, nbuck);

    bucket_rowsum_kernel<<<dim3(nbuck), 256, 0, stream>>>(
        h, base, epack, out, n_nodes, nbuck);
}